// Round 11
// baseline (500.615 us; speedup 1.0000x reference)
//
#include <hip/hip_runtime.h>
#include <hip/hip_bf16.h>

#define NN 131072   // nodes per side
#define NE 524288   // edges per side
#define NB 1024     // batch (graphs per side)

typedef __attribute__((ext_vector_type(8))) short short8;   // 8 bf16
typedef __attribute__((ext_vector_type(4))) float f32x4;

__device__ __forceinline__ float wsum(float v){
#pragma unroll
  for (int o = 32; o > 0; o >>= 1) v += __shfl_xor(v, o, 64);
  return v;
}
__device__ __forceinline__ short f2bs(float f){
  __hip_bfloat16 t = __float2bfloat16(f);
  union { __hip_bfloat16 b; short s; } u; u.b = t; return u.s;
}
__device__ __forceinline__ float bs2f(short s){
  return __uint_as_float(((unsigned)(unsigned short)s) << 16);
}
__device__ __forceinline__ float ulo2f(unsigned v){ return __uint_as_float(v << 16); }
__device__ __forceinline__ float uhi2f(unsigned v){ return __uint_as_float(v & 0xFFFF0000u); }
__device__ __forceinline__ unsigned fpack(float x, float y){
  return (unsigned)(unsigned short)f2bs(x) | ((unsigned)(unsigned short)f2bs(y) << 16);
}

// ---------------- mega: XCD-hist | frag pack | waA/ba/rtab | wconv | prep ----------------
__global__ void k_mega(int wconvB,
                       const int* __restrict__ u_ei, const int* __restrict__ i_ei,
                       int* __restrict__ cnt,
                       const float* __restrict__ wemb, unsigned* __restrict__ wtab,
                       int n32,
                       const float* __restrict__ cuW, const float* __restrict__ ciW,
                       const float* __restrict__ pW,
                       const float* __restrict__ cub, const float* __restrict__ cib,
                       const float* __restrict__ uatt, const float* __restrict__ iatt,
                       const float* __restrict__ urel, const float* __restrict__ irel,
                       short8* __restrict__ frag, float* __restrict__ waA,
                       float* __restrict__ ba, float* __restrict__ rtab,
                       const int* __restrict__ uid, const int* __restrict__ iid,
                       const float* __restrict__ uemb, const float* __restrict__ iemb,
                       const float* __restrict__ uiW, const float* __restrict__ uib,
                       const float* __restrict__ iiW, const float* __restrict__ iib,
                       const float* __restrict__ utW, const float* __restrict__ utb,
                       const float* __restrict__ itW, const float* __restrict__ itb,
                       float* __restrict__ xfm, float* __restrict__ q){
  const int histB = 8 * (2 * NE / 256);
  int blk = blockIdx.x, tid = threadIdx.x;
  if (blk < histB){
    int x = blk & 7;
    int ee = (blk >> 3) * 256 + tid;
    int side = ee >= NE;
    int e = ee - side * NE;
    const int* ei = side ? i_ei : u_ei;
    int dst = ei[NE + e] + side * NN;
    if ((dst >> 15) == x) atomicAdd(&cnt[dst], 1);
  } else if (blk < histB + 10){
    int b2 = blk - histB;
    int mat = b2 >> 1;
    const float* W = mat < 2 ? cuW + mat * 4096 : (mat < 4 ? ciW + (mat - 2) * 4096 : pW);
    int g = (b2 & 1) * 256 + tid;     // [0,512)
    int lane = g & 63, rest = g >> 6;
    int hh = rest & 1, t = rest >> 1;
    int m = lane & 15, qq = lane >> 4;
    short8 v;
#pragma unroll
    for (int j = 0; j < 8; j++)
      v[j] = f2bs(W[(hh * 32 + qq * 8 + j) * 64 + (t * 16 + m)]);
    frag[mat * 512 + g] = v;
  } else if (blk < histB + 12){
    int side = blk - histB - 10;
    const float* W    = side ? ciW : cuW;
    const float* bias = side ? cib : cub;
    const float* att  = side ? iatt : uatt;
    const float* rel  = side ? irel : urel;
    int l = tid >> 7, a = (tid >> 6) & 1, kk = tid & 63;
    float s = 0.f;
    for (int c = 0; c < 64; c++) s += W[l * 4096 + kk * 64 + c] * att[l * 192 + a * 64 + c];
    waA[((side * 2 + l) * 2 + a) * 64 + kk] = s;
    if (tid < 4){
      int l2 = tid >> 1, a2 = tid & 1;
      float sb = 0.f;
      for (int c = 0; c < 64; c++) sb += bias[l2 * 64 + c] * att[l2 * 192 + a2 * 64 + c];
      ba[(side * 2 + l2) * 2 + a2] = sb;
    }
    if (tid >= 4 && tid < 12){
      int id = tid - 4, l2 = id >> 2, tt = id & 3;
      float sr = 0.f;
      for (int c = 0; c < 64; c++) sr += rel[l2 * 256 + tt * 64 + c] * att[l2 * 192 + 128 + c];
      rtab[(side * 2 + l2) * 4 + tt] = sr;
    }
  } else if (blk < histB + 12 + wconvB){
    int id = (blk - histB - 12) * 256 + tid;
    if (id < n32){
      const float2* src = (const float2*)wemb;
      float2 v = src[id];
      wtab[id] = fpack(v.x, v.y);
    }
  } else {
    int lane = tid & 63, w = tid >> 6;
    int b = (blk - histB - 12 - wconvB) * 4 + w;   // [0, 2NB)
    int side = b >= NB;
    int lb = b - side * NB;
    const int* ids = side ? iid : uid;
    const float* emb = side ? iemb : uemb;
    const float* interW = side ? iiW : uiW;
    const float* interB = side ? iib : uib;
    const float* transW = side ? itW : utW;
    const float* transB = side ? itb : utb;
    int repOff = side ? 192 : 0;
    float xe = emb[(long)ids[lb] * 64 + lane];
    float o = interB[lane];
#pragma unroll
    for (int k = 0; k < 64; k++) o += __shfl(xe, k, 64) * interW[k * 64 + lane];
    xfm[lb * 384 + repOff + lane] = fmaxf(o, 0.f);
    for (int l = 0; l < 2; l++){
      float t = transB[l * 64 + lane];
#pragma unroll
      for (int k = 0; k < 64; k++) t += __shfl(xe, k, 64) * transW[l * 4096 + k * 64 + lane];
      q[((size_t)(side * 2 + l) * NB + lb) * 64 + lane] = fmaxf(t, 0.f);
    }
  }
}

__global__ void k_scan1(const int* __restrict__ cnt, int* __restrict__ rowptr,
                        int* __restrict__ bsum){
  __shared__ int sh[256];
  int i = blockIdx.x * 256 + threadIdx.x;
  int v = cnt[i];
  sh[threadIdx.x] = v; __syncthreads();
  for (int off = 1; off < 256; off <<= 1){
    int t = (threadIdx.x >= off) ? sh[threadIdx.x - off] : 0;
    __syncthreads();
    sh[threadIdx.x] += t;
    __syncthreads();
  }
  int incl = sh[threadIdx.x];
  rowptr[i] = incl - v;
  if (threadIdx.x == 255) bsum[blockIdx.x] = incl;
}

__global__ void k_scan2(int* __restrict__ bsum){
  __shared__ int sh[1024];
  int v = bsum[threadIdx.x];
  sh[threadIdx.x] = v; __syncthreads();
  for (int off = 1; off < 1024; off <<= 1){
    int t = (threadIdx.x >= off) ? sh[threadIdx.x - off] : 0;
    __syncthreads();
    sh[threadIdx.x] += t;
    __syncthreads();
  }
  bsum[threadIdx.x] = sh[threadIdx.x] - v;  // exclusive
}

__global__ void k_scan3(int* __restrict__ rowptr, const int* __restrict__ bsum,
                        int* __restrict__ cursor){
  int i = blockIdx.x * 256 + threadIdx.x;
  int v = rowptr[i] + bsum[blockIdx.x];
  rowptr[i] = v;
  cursor[i] = v;
  if (i == 0) rowptr[2 * NN] = 2 * NE;
}

// ---------------- scatter (XCD-partitioned) | word-level a0/a1 tables ----------------
__global__ void k_scw(const int* __restrict__ u_ei, const int* __restrict__ i_ei,
                      const int* __restrict__ u_et, const int* __restrict__ i_et,
                      int* __restrict__ cursor, int* __restrict__ pedge,
                      const short* __restrict__ wtab, int nwords,
                      const float* __restrict__ waA, const float* __restrict__ ba,
                      float* __restrict__ wa0, float* __restrict__ wa1){
  const int scatB = 8 * (2 * NE / 256);
  int blk = blockIdx.x, tid = threadIdx.x;
  if (blk < scatB){
    int x = blk & 7;
    int ee = (blk >> 3) * 256 + tid;
    int side = ee >= NE;
    int e = ee - side * NE;
    const int* ei = side ? i_ei : u_ei;
    int dst = ei[NE + e] + side * NN;
    if ((dst >> 15) == x){
      const int* et = side ? i_et : u_et;
      int src = ei[e] + side * NN;
      int p = atomicAdd(&cursor[dst], 1);
      pedge[p] = src | (et[e] << 18);
    }
  } else {
    // wa0/wa1[side][word] = wtab[word] . waA(side,l=0,a) + ba
    int lane = tid & 63, w = tid >> 6;
    int q = lane >> 4, cl = lane & 15;
    int sw0 = ((blk - scatB) * 4 + w) * 8;
    const uint2* wt2 = (const uint2*)wtab;
    for (int it = 0; it < 2; it++){
      int wj = sw0 + it * 4 + q;
      if (wj >= 2 * nwords) continue;
      int side = wj >= nwords;
      int wid = wj - side * nwords;
      const float* A0 = waA + (side * 2 + 0) * 2 * 64;
      const float* A1 = A0 + 64;
      uint2 v = wt2[(long)wid * 16 + cl];
      int d = 4 * cl;
      float p0 = ulo2f(v.x) * A0[d] + uhi2f(v.x) * A0[d + 1] +
                 ulo2f(v.y) * A0[d + 2] + uhi2f(v.y) * A0[d + 3];
      float p1 = ulo2f(v.x) * A1[d] + uhi2f(v.x) * A1[d + 1] +
                 ulo2f(v.y) * A1[d + 2] + uhi2f(v.y) * A1[d + 3];
      p0 += __shfl_xor(p0, 1, 64); p0 += __shfl_xor(p0, 2, 64);
      p0 += __shfl_xor(p0, 4, 64); p0 += __shfl_xor(p0, 8, 64);
      p1 += __shfl_xor(p1, 1, 64); p1 += __shfl_xor(p1, 2, 64);
      p1 += __shfl_xor(p1, 4, 64); p1 += __shfl_xor(p1, 8, 64);
      if (cl == 0){
        wa0[(size_t)side * nwords + wid] = p0 + ba[side * 4 + 0];
        wa1[(size_t)side * nwords + wid] = p1 + ba[side * 4 + 1];
      }
    }
  }
}

// ---------------- fused per-graph: agg(LDS) -> conv gemm -> gates -> pool -> trans_w ----------------
template<int L>
__device__ __forceinline__ void dev_fused(
    const int* __restrict__ rowptr, const int* __restrict__ pedge,
    const short* __restrict__ rows,
    const int* __restrict__ u_nodes, const int* __restrict__ i_nodes, int nwords,
    const float* __restrict__ wa0, const float* __restrict__ wa1,
    const float* __restrict__ a0in, const float* __restrict__ a1in,
    const float* __restrict__ rtab, const short8* __restrict__ frag,
    const float* __restrict__ cub, const float* __restrict__ cib,
    const float* __restrict__ waA_all, const float* __restrict__ ba_all,
    const float* __restrict__ qbuf, const float* __restrict__ twW_all,
    const float* __restrict__ twb_all, float* __restrict__ xfm,
    short* __restrict__ xnext, float* __restrict__ a0out, float* __restrict__ a1out){
  __shared__ short xa[128 * 72];       // aggregated input (padded rows)
  __shared__ short xc[128 * 72];       // conv output
  __shared__ float gates[128];
  __shared__ float red[4][64];
  int b = blockIdx.x;                  // [0, 2NB)
  int side = b >= NB;
  int g = b - side * NB;
  long nbase = (long)side * NN + (long)g * 128;
  int tid = threadIdx.x, lane = tid & 63, w = tid >> 6;
  int q = lane >> 4, cl = lane & 15, m = lane & 15;
  const float* rt = rtab + (side * 2 + L) * 4;
  float rt0 = rt[0], rt1 = rt[1], rt2 = rt[2], rt3 = rt[3];
  const int* nodesS = side ? i_nodes : u_nodes;
  const float* wa0S = wa0 + (size_t)side * nwords;
  const float* wa1S = wa1 + (size_t)side * nwords;

  // ---- phase 1: aggregation into xa; wave w owns rows w*32..w*32+31 ----
  // All loops are wave-uniform; quarter-owned nodes run to the max trip count
  // across the 4 quarters so every __shfl executes with all 64 lanes active.
  int rp = (lane < 33) ? rowptr[nbase + w * 32 + lane] : 0;
  float a1n = 0.f;
  if (lane < 32){
    long nidx = nbase + w * 32 + lane;
    if (L == 0) a1n = wa1S[nodesS[nidx - (long)side * NN]];
    else        a1n = a1in[nidx];
  }
  const uint2* r2 = (const uint2*)rows;
  unsigned* xa32 = (unsigned*)xa;
  for (int hh = 0; hh < 2; hh++){
    int rbase = __shfl(rp, hh * 16, 64);
    int rend  = __shfl(rp, hh * 16 + 16, 64);
    int tot = min(rend - rbase, 64);
    int eidx = rbase + lane;
    int pe = (lane < tot) ? pedge[eidx] : 0;
    int psrc = pe & 0x3FFFF;
    int prow = psrc; float pa0 = 0.f;
    if (L == 0){
      int wid = (lane < tot) ? nodesS[psrc - side * NN] : 0;
      prow = wid;
      if (lane < tot) pa0 = wa0S[wid];
    } else {
      if (lane < tot) pa0 = a0in[psrc];
    }
    int kn = 0;
#pragma unroll
    for (int t = 1; t < 16; t++)
      kn += (eidx >= __shfl(rp, hh * 16 + t, 64)) ? 1 : 0;
    float a1e = __shfl(a1n, hh * 16 + kn, 64);
    int pet = (pe >> 18) & 3;
    float rr = (pet & 2) ? ((pet & 1) ? rt3 : rt2) : ((pet & 1) ? rt1 : rt0);
    float vv = pa0 + a1e + rr;
    vv = (vv > 0.f) ? vv : 0.2f * vv;
    float pex = (lane < tot) ? __expf(vv) : 0.f;
#pragma unroll
    for (int it = 0; it < 4; it++){
      int nl = hh * 16 + it * 4 + q;               // quarter-per-node
      int r0 = __shfl(rp, nl, 64), r1 = __shfl(rp, nl + 1, 64);
      float a1k = __shfl(a1n, nl, 64);
      int trips = r1 - r0;                          // quarter-uniform
      int mt = max(trips, __shfl_xor(trips, 16, 64));
      mt = max(mt, __shfl_xor(mt, 32, 64));         // wave-uniform max
      float ax0 = 0.f, ay0 = 0.f, ax1 = 0.f, ay1 = 0.f, den = 0.f;
      for (int i = 0; i < mt; i++){                 // wave-uniform loop
        int e = r0 + i;
        bool ok = i < trips;
        int idx = e - rbase;
        int idxc = (idx < 64 && idx >= 0) ? idx : 0;
        int s = __shfl(prow, idxc, 64);             // all lanes active
        float ex = __shfl(pex, idxc, 64);
        if (ok && idx >= 64){                       // rare spill past window
          int pe2 = pedge[e];
          int s2 = pe2 & 0x3FFFF;
          int et2 = (pe2 >> 18) & 3;
          float rv = (et2 & 2) ? ((et2 & 1) ? rt3 : rt2) : ((et2 & 1) ? rt1 : rt0);
          float av;
          if (L == 0){ int wid = nodesS[s2 - side * NN]; av = wa0S[wid]; s = wid; }
          else       { av = a0in[s2]; s = s2; }
          float v2 = av + a1k + rv;
          v2 = (v2 > 0.f) ? v2 : 0.2f * v2;
          ex = __expf(v2);
        }
        if (ok){
          uint2 v = r2[(long)s * 16 + cl];
          ax0 += ex * ulo2f(v.x); ay0 += ex * uhi2f(v.x);
          ax1 += ex * ulo2f(v.y); ay1 += ex * uhi2f(v.y);
          den += ex;
        }
      }
      float inv = 1.f / (den + 1e-16f);
      int row = w * 32 + nl;
      xa32[row * 36 + 2 * cl]     = fpack(ax0 * inv, ay0 * inv);
      xa32[row * 36 + 2 * cl + 1] = fpack(ax1 * inv, ay1 * inv);
    }
  }
  __syncthreads();

  // ---- phase 2: conv GEMM (A from xa LDS), relu, write xc ----
  const short8* wfrag = frag + (side * 2 + L) * 512;
  const float* bias = (side ? cib : cub) + L * 64;
  short8 Bf[4][2];
#pragma unroll
  for (int t = 0; t < 4; t++)
#pragma unroll
    for (int hh = 0; hh < 2; hh++)
      Bf[t][hh] = wfrag[(t * 2 + hh) * 64 + lane];
  float bs4[4];
#pragma unroll
  for (int t = 0; t < 4; t++) bs4[t] = bias[t * 16 + m];
  f32x4 accA[2][4];
#pragma unroll
  for (int rb = 0; rb < 2; rb++){
    int rowb = w * 32 + rb * 16;
    short8 A0 = *(const short8*)(xa + (rowb + m) * 72 + q * 8);
    short8 A1 = *(const short8*)(xa + (rowb + m) * 72 + 32 + q * 8);
#pragma unroll
    for (int t = 0; t < 4; t++){
      f32x4 acc = (f32x4){bs4[t], bs4[t], bs4[t], bs4[t]};
      acc = __builtin_amdgcn_mfma_f32_16x16x32_bf16(A0, Bf[t][0], acc, 0, 0, 0);
      acc = __builtin_amdgcn_mfma_f32_16x16x32_bf16(A1, Bf[t][1], acc, 0, 0, 0);
#pragma unroll
      for (int r = 0; r < 4; r++) acc[r] = fmaxf(acc[r], 0.f);
      accA[rb][t] = acc;
#pragma unroll
      for (int r = 0; r < 4; r++)
        xc[(rowb + q * 4 + r) * 72 + t * 16 + m] = f2bs(acc[r]);
    }
  }
  __syncthreads();

  // ---- phase 3: pool GEMM from xc -> gates ----
  const short8* pfrag = frag + 4 * 512;
  const float* qv_ = qbuf + ((size_t)(side * 2 + L) * NB + g) * 64;
  short8 Pf[4][2];
#pragma unroll
  for (int t = 0; t < 4; t++)
#pragma unroll
    for (int hh = 0; hh < 2; hh++)
      Pf[t][hh] = pfrag[(t * 2 + hh) * 64 + lane];
  float qv[4];
#pragma unroll
  for (int t = 0; t < 4; t++) qv[t] = qv_[t * 16 + m];
#pragma unroll
  for (int rb = 0; rb < 2; rb++){
    int rowb = w * 32 + rb * 16;
    short8 A0 = *(const short8*)(xc + (rowb + m) * 72 + q * 8);
    short8 A1 = *(const short8*)(xc + (rowb + m) * 72 + 32 + q * 8);
    f32x4 accp[4];
#pragma unroll
    for (int t = 0; t < 4; t++){
      accp[t] = (f32x4){0.f, 0.f, 0.f, 0.f};
      accp[t] = __builtin_amdgcn_mfma_f32_16x16x32_bf16(A0, Pf[t][0], accp[t], 0, 0, 0);
      accp[t] = __builtin_amdgcn_mfma_f32_16x16x32_bf16(A1, Pf[t][1], accp[t], 0, 0, 0);
    }
#pragma unroll
    for (int r = 0; r < 4; r++){
      float p = accp[0][r] * qv[0] + accp[1][r] * qv[1] +
                accp[2][r] * qv[2] + accp[3][r] * qv[3];
      p += __shfl_xor(p, 1, 64); p += __shfl_xor(p, 2, 64);
      p += __shfl_xor(p, 4, 64); p += __shfl_xor(p, 8, 64);
      if (m == 0)
        gates[rowb + q * 4 + r] = 1.f / (1.f + __expf(-p * 0.125f));
    }
  }
  __syncthreads();

  // ---- phase 4: gated max pool + trans_w ----
  const unsigned* xc32 = (const unsigned*)xc;
  int c = lane & 31, half = lane >> 5;
  float mxx = 0.f, mxy = 0.f;
#pragma unroll
  for (int p = 0; p < 16; p++){
    int nn = w * 32 + 2 * p + half;
    unsigned v = xc32[nn * 36 + c];
    float gt = gates[nn];
    mxx = fmaxf(mxx, ulo2f(v) * gt);
    mxy = fmaxf(mxy, uhi2f(v) * gt);
  }
  mxx = fmaxf(mxx, __shfl_xor(mxx, 32, 64));
  mxy = fmaxf(mxy, __shfl_xor(mxy, 32, 64));
  if (half == 0){ red[w][2 * c] = mxx; red[w][2 * c + 1] = mxy; }
  __syncthreads();
  if (tid < 64){
    const float* twW = twW_all + L * 4096;
    const float* twb = twb_all + L * 64;
    int off = (side ? 256 : 64) + L * 64;
    float p = fmaxf(fmaxf(red[0][tid], red[1][tid]), fmaxf(red[2][tid], red[3][tid]));
    float o = twb[tid];
    red[0][tid] = p;
    __syncwarp();
    for (int d = 0; d < 64; d++) o += red[0][d] * twW[d * 64 + tid];
    xfm[g * 384 + off + tid] = fmaxf(o, 0.f);
  }

  // ---- phase 5 (L==0): gated next-layer input + a0/a1 epilogue ----
  if (L == 0){
#pragma unroll
    for (int p = 0; p < 4; p++){
      int row = p * 32 + (tid >> 3);
      int col8 = (tid & 7) * 8;
      float gt = gates[row];
      short8 v = *(const short8*)(xc + row * 72 + col8);
      short8 o;
#pragma unroll
      for (int j = 0; j < 8; j++) o[j] = f2bs(bs2f(v[j]) * gt);
      *(short8*)(xnext + (nbase + row) * 64 + col8) = o;
    }
    const float* wn0p = waA_all + ((side * 2 + 1) * 2 + 0) * 64;
    const float* wn1p = wn0p + 64;
    float wn0[4], wn1[4];
#pragma unroll
    for (int t = 0; t < 4; t++){ wn0[t] = wn0p[t * 16 + m]; wn1[t] = wn1p[t * 16 + m]; }
    float ban0 = ba_all[(side * 2 + 1) * 2 + 0];
    float ban1 = ba_all[(side * 2 + 1) * 2 + 1];
#pragma unroll
    for (int rb = 0; rb < 2; rb++)
#pragma unroll
      for (int r = 0; r < 4; r++){
        float p0 = accA[rb][0][r] * wn0[0] + accA[rb][1][r] * wn0[1] +
                   accA[rb][2][r] * wn0[2] + accA[rb][3][r] * wn0[3];
        float p1 = accA[rb][0][r] * wn1[0] + accA[rb][1][r] * wn1[1] +
                   accA[rb][2][r] * wn1[2] + accA[rb][3][r] * wn1[3];
        p0 += __shfl_xor(p0, 1, 64); p0 += __shfl_xor(p0, 2, 64);
        p0 += __shfl_xor(p0, 4, 64); p0 += __shfl_xor(p0, 8, 64);
        p1 += __shfl_xor(p1, 1, 64); p1 += __shfl_xor(p1, 2, 64);
        p1 += __shfl_xor(p1, 4, 64); p1 += __shfl_xor(p1, 8, 64);
        if (m == 0){
          int row = w * 32 + rb * 16 + q * 4 + r;
          float gr = gates[row];
          a0out[nbase + row] = p0 * gr + ban0;
          a1out[nbase + row] = p1 * gr + ban1;
        }
      }
  }
}

__global__ __launch_bounds__(256) void kf0(
    const int* __restrict__ rowptr, const int* __restrict__ pedge,
    const short* __restrict__ wtab,
    const int* __restrict__ u_nodes, const int* __restrict__ i_nodes, int nwords,
    const float* __restrict__ wa0, const float* __restrict__ wa1,
    const float* __restrict__ rtab, const short8* __restrict__ frag,
    const float* __restrict__ cub, const float* __restrict__ cib,
    const float* __restrict__ waA, const float* __restrict__ ba,
    const float* __restrict__ qbuf, const float* __restrict__ twW,
    const float* __restrict__ twb, float* __restrict__ xfm,
    short* __restrict__ xnext, float* __restrict__ a0out, float* __restrict__ a1out){
  dev_fused<0>(rowptr, pedge, wtab, u_nodes, i_nodes, nwords, wa0, wa1,
               nullptr, nullptr, rtab, frag, cub, cib, waA, ba, qbuf,
               twW, twb, xfm, xnext, a0out, a1out);
}

__global__ __launch_bounds__(256) void kf1(
    const int* __restrict__ rowptr, const int* __restrict__ pedge,
    const short* __restrict__ x1,
    const float* __restrict__ a0in, const float* __restrict__ a1in,
    const float* __restrict__ rtab, const short8* __restrict__ frag,
    const float* __restrict__ cub, const float* __restrict__ cib,
    const float* __restrict__ waA, const float* __restrict__ ba,
    const float* __restrict__ qbuf, const float* __restrict__ twW,
    const float* __restrict__ twb, float* __restrict__ xfm){
  dev_fused<1>(rowptr, pedge, x1, nullptr, nullptr, 0, nullptr, nullptr,
               a0in, a1in, rtab, frag, cub, cib, waA, ba, qbuf,
               twW, twb, xfm, nullptr, nullptr, nullptr);
}

// ---------------- FM head: 4 graphs per block, V streamed once per block ----------------
__global__ __launch_bounds__(384) void k_fm(
    const float* __restrict__ xfm, const float* __restrict__ V,
    const float* __restrict__ fw, const float* __restrict__ bu,
    const float* __restrict__ bi, const float* __restrict__ b0,
    const int* __restrict__ uid, const int* __restrict__ iid,
    float* __restrict__ out){
  __shared__ float xsh[4][384];
  __shared__ float xsq[4][384];
  __shared__ float part[4][384];
  int j = threadIdx.x;
  int g0 = blockIdx.x * 4;
#pragma unroll
  for (int b = 0; b < 4; b++){
    float xv_ = xfm[(g0 + b) * 384 + j];
    xsh[b][j] = xv_;
    xsq[b][j] = xv_ * xv_;
  }
  __syncthreads();
  float xv[4] = {0.f, 0.f, 0.f, 0.f};
  float vv[4] = {0.f, 0.f, 0.f, 0.f};
  for (int k = 0; k < 384; k++){
    float v = V[(size_t)k * 384 + j];
    float v2 = v * v;
#pragma unroll
    for (int b = 0; b < 4; b++){
      xv[b] = fmaf(xsh[b][k], v, xv[b]);
      vv[b] = fmaf(xsq[b][k], v2, vv[b]);
    }
  }
  float fwj = fw[j];
#pragma unroll
  for (int b = 0; b < 4; b++)
    part[b][j] = 0.5f * (xv[b] * xv[b] - vv[b]) + xsh[b][j] * fwj;
  __syncthreads();
  int w = j >> 6, lane = j & 63;
  if (w < 4){
    float s = part[w][lane] + part[w][lane + 64] + part[w][lane + 128] +
              part[w][lane + 192] + part[w][lane + 256] + part[w][lane + 320];
    s = wsum(s);
    if (lane == 0){
      int b = g0 + w;
      out[b] = s + bu[uid[b]] + bi[iid[b]] + b0[0];
    }
  }
}

extern "C" void kernel_launch(void* const* d_in, const int* in_sizes, int n_in,
                              void* d_out, int out_size, void* d_ws, size_t ws_size,
                              hipStream_t stream) {
  const int* uid      = (const int*)d_in[0];
  const int* iid      = (const int*)d_in[1];
  const int* u_nodes  = (const int*)d_in[2];
  const int* i_nodes  = (const int*)d_in[3];
  const int* u_ei     = (const int*)d_in[4];
  const int* i_ei     = (const int*)d_in[5];
  const int* u_et     = (const int*)d_in[6];
  const int* i_et     = (const int*)d_in[7];
  const float* user_emb = (const float*)d_in[10];
  const float* item_emb = (const float*)d_in[11];
  const float* word_emb = (const float*)d_in[12];
  const float* trans_u_W = (const float*)d_in[13];
  const float* trans_u_b = (const float*)d_in[14];
  const float* trans_i_W = (const float*)d_in[15];
  const float* trans_i_b = (const float*)d_in[16];
  const float* trans_w_W = (const float*)d_in[17];
  const float* trans_w_b = (const float*)d_in[18];
  const float* inter_u_W = (const float*)d_in[19];
  const float* inter_u_b = (const float*)d_in[20];
  const float* inter_i_W = (const float*)d_in[21];
  const float* inter_i_b = (const float*)d_in[22];
  const float* conv_u_W  = (const float*)d_in[23];
  const float* conv_u_b  = (const float*)d_in[24];
  const float* conv_u_att= (const float*)d_in[25];
  const float* conv_u_rel= (const float*)d_in[26];
  const float* conv_i_W  = (const float*)d_in[27];
  const float* conv_i_b  = (const float*)d_in[28];
  const float* conv_i_att= (const float*)d_in[29];
  const float* conv_i_rel= (const float*)d_in[30];
  const float* pool_W    = (const float*)d_in[31];
  const float* fm_w      = (const float*)d_in[32];
  const float* fm_V      = (const float*)d_in[33];
  const float* fm_bias_u = (const float*)d_in[34];
  const float* fm_bias_i = (const float*)d_in[35];
  const float* fm_bias   = (const float*)d_in[36];
  float* out = (float*)d_out;
  int n32 = in_sizes[12] / 2;          // packed uints in word table
  int nwords = in_sizes[12] / 64;      // words (HID=64)
  int wconvB = (n32 + 255) / 256;

  // workspace carve-up
  char* w = (char*)d_ws;
  short* X1   = (short*)w;          w += (size_t)2 * NN * 64 * 2;   // 32 MB
  short* wtab = (short*)w;          w += (size_t)in_sizes[12] * 2;  // bf16 word table
  int* pedge  = (int*)w;            w += (size_t)2 * NE * 4;
  float* a0   = (float*)w;          w += (size_t)2 * NN * 4;
  float* a1   = (float*)w;          w += (size_t)2 * NN * 4;
  float* wa0  = (float*)w;          w += (size_t)2 * nwords * 4;
  float* wa1  = (float*)w;          w += (size_t)2 * nwords * 4;
  int* rowptr = (int*)w;            w += (size_t)(2 * NN + 256) * 4;
  int* cursor = (int*)w;            w += (size_t)2 * NN * 4;
  int* cnt    = (int*)w;            w += (size_t)2 * NN * 4;
  int* bsum   = (int*)w;            w += 1024 * 4;
  short8* frag = (short8*)w;        w += (size_t)5 * 512 * 16;
  float* waA  = (float*)w;          w += 2 * 2 * 2 * 64 * 4;
  float* ba   = (float*)w;          w += 64;
  float* rtab = (float*)w;          w += 64;
  float* qbuf = (float*)w;          w += (size_t)4 * NB * 64 * 4;
  float* xfm  = (float*)w;          w += (size_t)NB * 384 * 4;

  hipMemsetAsync(cnt, 0, (size_t)2 * NN * 4, stream);

  int histB = 8 * (2 * NE / 256);
  int megaB = histB + 12 + wconvB + 2 * NB / 4;
  k_mega<<<megaB, 256, 0, stream>>>(wconvB, u_ei, i_ei, cnt,
                                    word_emb, (unsigned*)wtab, n32,
                                    conv_u_W, conv_i_W, pool_W, conv_u_b, conv_i_b,
                                    conv_u_att, conv_i_att, conv_u_rel, conv_i_rel,
                                    frag, waA, ba, rtab,
                                    uid, iid, user_emb, item_emb,
                                    inter_u_W, inter_u_b, inter_i_W, inter_i_b,
                                    trans_u_W, trans_u_b, trans_i_W, trans_i_b,
                                    xfm, qbuf);
  k_scan1<<<2 * NN / 256, 256, 0, stream>>>(cnt, rowptr, bsum);
  k_scan2<<<1, 1024, 0, stream>>>(bsum);
  k_scan3<<<2 * NN / 256, 256, 0, stream>>>(rowptr, bsum, cursor);
  int wgB = (2 * nwords + 31) / 32;
  k_scw<<<histB + wgB, 256, 0, stream>>>(u_ei, i_ei, u_et, i_et, cursor, pedge,
                                         wtab, nwords, waA, ba, wa0, wa1);

  kf0<<<2 * NB, 256, 0, stream>>>(rowptr, pedge, wtab, u_nodes, i_nodes, nwords,
                                  wa0, wa1, rtab, frag, conv_u_b, conv_i_b,
                                  waA, ba, qbuf, trans_w_W, trans_w_b, xfm,
                                  X1, a0, a1);
  kf1<<<2 * NB, 256, 0, stream>>>(rowptr, pedge, X1, a0, a1, rtab, frag,
                                  conv_u_b, conv_i_b, waA, ba, qbuf,
                                  trans_w_W, trans_w_b, xfm);

  k_fm<<<NB / 4, 384, 0, stream>>>(xfm, fm_V, fm_w, fm_bias_u, fm_bias_i, fm_bias,
                                   uid, iid, out);
}